// Round 9
// baseline (387.732 us; speedup 1.0000x reference)
//
#include <hip/hip_runtime.h>
#include <math.h>

// ============ MEASUREMENT BUILD ============
// REP=8 inner repeats per kernel (idempotent; identical final results) to
// lift every kernel above the ~41 µs harness fills in rocprof top-5 and
// recover per-kernel dur + counters. Functional output is bit-identical to
// the r8 kernel (best: 148.8 µs). Next round reverts REP to 1 and applies
// the data-driven fix.
#define REP 8

#define NZ    128
#define H1    512
#define H2    1024
#define IMG   784
#define IMGP  896     // layer-3 N padded to 7*128
#define BATCH 4096
#define NGEN  10
#define MPAD  128     // packed-row slack so tail tiles can stage past ng

typedef _Float16 f16;
typedef __attribute__((ext_vector_type(8))) _Float16 half8;
typedef __attribute__((ext_vector_type(4))) float floatx4;

// transpose tile counts (64x64 tiles)
#define TB1 ((NZ / 64) * (H1 / 64) * NGEN)    // 160
#define TB2 ((H1 / 64) * (H2 / 64) * NGEN)    // 1280
#define TB3 ((H2 / 64) * (IMGP / 64) * NGEN)  // 2240

// GEMM logical grids (NM=8 m-tiles covers any bucket <= 1024 rows)
#define NWG1 (8 * 4 * NGEN)                   // 320
#define NWG2 (8 * 8 * NGEN)                   // 640
#define NWG3 (8 * 7 * NGEN)                   // 560

__device__ __forceinline__ void cp16(void* l, const void* g) {
    __builtin_amdgcn_global_load_lds((const __attribute__((address_space(1))) void*)g,
                                     (__attribute__((address_space(3))) void*)l, 16, 0, 0);
}

// ---------------- 256-thread transpose tile (prep1 only) ----------------
template<int K, int N, int NPAD>
__device__ void t_tile256(int idx, const float* __restrict__ W,
                          f16* __restrict__ Wt, f16 (*L)[72]) {
    constexpr int KT = K / 64, NTt = NPAD / 64;
    const int g  = idx / (KT * NTt);
    const int r2 = idx % (KT * NTt);
    const int k0 = (r2 % KT) * 64;
    const int n0 = (r2 / KT) * 64;
    const int t = threadIdx.x;
    for (int rep = 0; rep < REP; ++rep) {
        __syncthreads();                   // cross-rep LDS reuse guard
        {
            const int kk0 = t >> 4, nq = (t & 15) * 4;
            #pragma unroll
            for (int it = 0; it < 4; ++it) {
                const int kk = kk0 + it * 16;
                float4 v = make_float4(0.f, 0.f, 0.f, 0.f);
                if (n0 + nq < N)           // N % 4 == 0: quads never straddle
                    v = *(const float4*)(W + ((size_t)g * K + (k0 + kk)) * N + n0 + nq);
                L[nq + 0][kk] = (f16)v.x;
                L[nq + 1][kk] = (f16)v.y;
                L[nq + 2][kk] = (f16)v.z;
                L[nq + 3][kk] = (f16)v.w;
            }
        }
        __syncthreads();
        {
            const int nn0 = t >> 3, kq = (t & 7) * 8;
            #pragma unroll
            for (int it = 0; it < 2; ++it) {
                const int nn = nn0 + it * 32;
                *(half8*)(Wt + ((size_t)g * NPAD + (n0 + nn)) * K + k0 + kq) =
                    *(const half8*)&L[nn][kq];
            }
        }
    }
}

// ---------------- 512-thread transpose tile (fused into GEMM launches) ----------
template<int K, int N, int NPAD>
__device__ void t_tile512(int idx, const float* __restrict__ W,
                          f16* __restrict__ Wt, char* smraw) {
    f16 (*L)[72] = (f16(*)[72])smraw;      // 9 KB of the 64 KB union
    constexpr int KT = K / 64, NTt = NPAD / 64;
    const int g  = idx / (KT * NTt);
    const int r2 = idx % (KT * NTt);
    const int k0 = (r2 % KT) * 64;
    const int n0 = (r2 / KT) * 64;
    const int t = threadIdx.x;
    for (int rep = 0; rep < REP; ++rep) {
        __syncthreads();                   // cross-rep LDS reuse guard
        {
            const int kk0 = t >> 4;        // 0..31
            const int nq  = (t & 15) * 4;
            #pragma unroll
            for (int it = 0; it < 2; ++it) {
                const int kk = kk0 + it * 32;
                float4 v = make_float4(0.f, 0.f, 0.f, 0.f);
                if (n0 + nq < N)
                    v = *(const float4*)(W + ((size_t)g * K + (k0 + kk)) * N + n0 + nq);
                L[nq + 0][kk] = (f16)v.x;
                L[nq + 1][kk] = (f16)v.y;
                L[nq + 2][kk] = (f16)v.z;
                L[nq + 3][kk] = (f16)v.w;
            }
        }
        __syncthreads();
        {
            const int nn = t >> 3, kq = (t & 7) * 8;   // 64 rows x 8 quads
            *(half8*)(Wt + ((size_t)g * NPAD + (n0 + nn)) * K + k0 + kq) =
                *(const half8*)&L[nn][kq];
        }
    }
}

// ---------------- prep1: block 0 = hist+perm, blocks 1.. = W1 transpose ----------
__global__ __launch_bounds__(256)
void prep1(const float* __restrict__ W1, f16* __restrict__ W1t,
           const int* __restrict__ g_idx, int* __restrict__ seg,
           int* __restrict__ perm) {
    __shared__ f16 L[64][72];
    __shared__ int lc[NGEN];
    __shared__ int lb[NGEN + 1];
    const int bid = blockIdx.x;
    if (bid == 0) {
        const int t = threadIdx.x;
        if (t < NGEN) lc[t] = 0;
        __syncthreads();
        int gv[BATCH / 256];
        #pragma unroll
        for (int i = 0; i < BATCH / 256; ++i) {
            gv[i] = g_idx[t + i * 256];
            atomicAdd(&lc[gv[i]], 1);
        }
        __syncthreads();
        if (t == 0) {
            int s = 0;
            for (int g = 0; g < NGEN; ++g) { lb[g] = s; s += lc[g]; }
            lb[NGEN] = s;
        }
        __syncthreads();
        if (t <= NGEN) seg[t] = lb[t];
        if (t < NGEN) lc[t] = lb[t];      // reuse as cursors
        __syncthreads();
        #pragma unroll
        for (int i = 0; i < BATCH / 256; ++i) {
            int p = atomicAdd(&lc[gv[i]], 1);
            perm[p] = t + i * 256;
        }
        return;
    }
    t_tile256<NZ, H1, H1>(bid - 1, W1, W1t, L);
}

// ---------------- 8-wave 128x128 GEMM item, r8 schedule (BK=64, 2 buffers) -------
template<int K, int NOUT, int NPADB, int NM, int NN, int ACT, int SCATTER>
__device__ void gemm8(int Lw, const f16* __restrict__ Ap,
                      const f16* __restrict__ Wt, const float* __restrict__ bias,
                      f16* __restrict__ Ch, float* __restrict__ Cout,
                      const int* __restrict__ seg, const int* __restrict__ perm,
                      char* smraw) {
    constexpr int NT = K / 64;
    static_assert((NT & 1) == 0, "rep wrap assumes even NT (last reads from buf1)");
    const int g   = Lw / (NM * NN);
    const int rem = Lw - g * (NM * NN);
    const int nt  = rem / NM;
    const int mt0 = rem - nt * NM;
    const int s0 = seg[g];
    const int ng = seg[g + 1] - s0;
    const int m0 = mt0 * 128;
    if (m0 >= ng) return;                 // block-uniform early exit
    const int n0 = nt * 128;

    f16* As = (f16*)smraw;                // [2][8192]
    f16* Bs = (f16*)(smraw + 32768);      // [2][8192]
    const int tid = threadIdx.x, lane = tid & 63, w = tid >> 6;

    const f16* ga[2]; const f16* gb[2]; int lo[2];
    #pragma unroll
    for (int j = 0; j < 2; ++j) {
        const int r   = w * 16 + j * 8 + (lane >> 3);
        const int swz = ((lane & 7) ^ ((r >> 1) & 7)) * 8;
        ga[j] = Ap + (size_t)(s0 + m0 + r) * K + swz;
        gb[j] = Wt + ((size_t)g * NPADB + n0 + r) * K + swz;
        lo[j] = (w * 16 + j * 8) * 64;
    }

    const int wm = (w & 1) * 64, wn = (w >> 1) * 32;
    const int lm = lane & 15, lq = lane >> 4;

    const int c = n0 + wn + 2 * lm;
    const bool in0 = (!SCATTER) || (c < NOUT);
    const float* bg = bias + (size_t)g * NOUT;
    const float bv0 = in0 ? bg[c]     : 0.f;
    const float bv1 = in0 ? bg[c + 1] : 0.f;

    floatx4 acc[4][2];

    auto stage = [&](int t, int b) {
        #pragma unroll
        for (int j = 0; j < 2; ++j) cp16(&As[b * 8192 + lo[j]], ga[j] + (size_t)t * 64);
        #pragma unroll
        for (int j = 0; j < 2; ++j) cp16(&Bs[b * 8192 + lo[j]], gb[j] + (size_t)t * 64);
    };

    for (int rep = 0; rep < REP; ++rep) {
        __syncthreads();                  // cross-rep: all prior LDS reads done
        #pragma unroll
        for (int mt = 0; mt < 4; ++mt)
            #pragma unroll
            for (int nf = 0; nf < 2; ++nf)
                acc[mt][nf] = (floatx4){0.f, 0.f, 0.f, 0.f};

        stage(0, 0);
        __builtin_amdgcn_sched_barrier(0);
        stage(1, 1);

        for (int kc = 0; kc < NT; ++kc) {
            if (kc + 1 < NT) asm volatile("s_waitcnt vmcnt(4)" ::: "memory");
            else             asm volatile("s_waitcnt vmcnt(0)" ::: "memory");
            __builtin_amdgcn_sched_barrier(0);
            __builtin_amdgcn_s_barrier();
            __builtin_amdgcn_sched_barrier(0);

            const int cb = (kc & 1) * 8192;
            half8 a[2][4], b[2][2];
            #pragma unroll
            for (int ks = 0; ks < 2; ++ks) {
                #pragma unroll
                for (int mt = 0; mt < 4; ++mt) {
                    const int r  = wm + mt * 16 + lm;
                    const int pq = (ks * 4 + lq) ^ ((r >> 1) & 7);
                    a[ks][mt] = *(const half8*)&As[cb + r * 64 + pq * 8];
                }
                #pragma unroll
                for (int nf = 0; nf < 2; ++nf) {
                    const int r  = wn + 2 * lm + nf;
                    const int pq = (ks * 4 + lq) ^ ((r >> 1) & 7);
                    b[ks][nf] = *(const half8*)&Bs[cb + r * 64 + pq * 8];
                }
            }
            asm volatile("s_waitcnt lgkmcnt(0)" ::: "memory");
            __builtin_amdgcn_sched_barrier(0);
            if (kc + 2 < NT) {
                __builtin_amdgcn_s_barrier();
                __builtin_amdgcn_sched_barrier(0);
                stage(kc + 2, kc & 1);
            }
            #pragma unroll
            for (int ks = 0; ks < 2; ++ks)
                #pragma unroll
                for (int mt = 0; mt < 4; ++mt)
                    #pragma unroll
                    for (int nf = 0; nf < 2; ++nf)
                        acc[mt][nf] = __builtin_amdgcn_mfma_f32_16x16x32_f16(
                            a[ks][mt], b[ks][nf], acc[mt][nf], 0, 0, 0);
        }
    }

    // epilogue (once; final rep's acc is the canonical result)
    #pragma unroll
    for (int mt = 0; mt < 4; ++mt)
        #pragma unroll
        for (int rr = 0; rr < 4; ++rr) {
            const int gr = m0 + wm + mt * 16 + lq * 4 + rr;
            if (gr >= ng) continue;
            float x0 = acc[mt][0][rr] + bv0;
            float x1 = acc[mt][1][rr] + bv1;
            if (ACT == 0) {
                x0 = fmaxf(x0, 0.f); x1 = fmaxf(x1, 0.f);
            } else {                      // tanh, inf-safe
                const float e0 = __expf(2.f * x0);
                const float e1 = __expf(2.f * x1);
                x0 = 1.f - 2.f / (e0 + 1.f);
                x1 = 1.f - 2.f / (e1 + 1.f);
            }
            if (SCATTER) {
                if (in0) {
                    const size_t orow = (size_t)perm[s0 + gr];
                    *(float2*)&Cout[orow * NOUT + c] = make_float2(x0, x1);
                }
            } else {
                union { uint u; f16 h[2]; } o;
                o.h[0] = (f16)x0; o.h[1] = (f16)x1;
                *(uint*)&Ch[(size_t)(s0 + gr) * NOUT + c] = o.u;
            }
        }
}

// ---------------- layer-1 item (512 threads): K=128, both tiles up-front --------
__device__ void l1_item(int Lw, const float* __restrict__ Az,
                        const f16* __restrict__ Wt, const float* __restrict__ bias,
                        f16* __restrict__ Ch, const int* __restrict__ seg,
                        const int* __restrict__ perm, char* smraw) {
    constexpr int K = NZ, NOUT = H1, NPADB = H1, NM = 8, NN = 4;
    const int g   = Lw / (NM * NN);
    const int rem = Lw - g * (NM * NN);
    const int nt  = rem / NM;
    const int mt0 = rem - nt * NM;
    const int s0 = seg[g];
    const int ng = seg[g + 1] - s0;
    const int m0 = mt0 * 128;
    if (m0 >= ng) return;
    const int n0 = nt * 128;

    f16* As = (f16*)smraw;
    f16* Bs = (f16*)(smraw + 32768);
    const int tid = threadIdx.x, lane = tid & 63, w = tid >> 6;

    const int wm = (w & 1) * 64, wn = (w >> 1) * 32;
    const int lm = lane & 15, lq = lane >> 4;
    const int c = n0 + wn + 2 * lm;
    const float* bg = bias + (size_t)g * NOUT;
    const float bv0 = bg[c], bv1 = bg[c + 1];

    floatx4 acc[4][2];

    for (int rep = 0; rep < REP; ++rep) {
        __syncthreads();                  // cross-rep LDS reuse guard
        #pragma unroll
        for (int mt = 0; mt < 4; ++mt)
            #pragma unroll
            for (int nf = 0; nf < 2; ++nf)
                acc[mt][nf] = (floatx4){0.f, 0.f, 0.f, 0.f};

        // B: both K-tiles via cp16; wave w stages rows [w*16, w*16+16)
        #pragma unroll
        for (int j = 0; j < 2; ++j) {
            const int r   = w * 16 + j * 8 + (lane >> 3);
            const int swz = ((lane & 7) ^ ((r >> 1) & 7)) * 8;
            const f16* gbj = Wt + ((size_t)g * NPADB + n0 + r) * K + swz;
            const int  loj = (w * 16 + j * 8) * 64;
            cp16(&Bs[loj],        gbj);
            cp16(&Bs[8192 + loj], gbj + 64);
        }
        // A: gather z rows via perm, convert f32->f16, swizzled ds_write.
        const int arow = tid >> 3, aq = tid & 7;
        #pragma unroll
        for (int p = 0; p < 2; ++p) {
            const int r   = arow + p * 64;
            const int prw = perm[min(s0 + m0 + r, BATCH - 1)];  // clamp off slack
            #pragma unroll
            for (int t = 0; t < 2; ++t) {
                const float* src = Az + (size_t)prw * K + t * 64 + aq * 8;
                const float4 v0 = *(const float4*)src;
                const float4 v1 = *(const float4*)(src + 4);
                half8 h;
                h[0] = (f16)v0.x; h[1] = (f16)v0.y; h[2] = (f16)v0.z; h[3] = (f16)v0.w;
                h[4] = (f16)v1.x; h[5] = (f16)v1.y; h[6] = (f16)v1.z; h[7] = (f16)v1.w;
                const int pq = aq ^ ((r >> 1) & 7);
                *(half8*)&As[t * 8192 + r * 64 + pq * 8] = h;
            }
        }

        __syncthreads();                  // drains cp16 + ds_write

        #pragma unroll
        for (int kc = 0; kc < 2; ++kc) {
            const int cb = kc * 8192;
            half8 a[2][4], b[2][2];
            #pragma unroll
            for (int ks = 0; ks < 2; ++ks) {
                #pragma unroll
                for (int mt = 0; mt < 4; ++mt) {
                    const int r  = wm + mt * 16 + lm;
                    const int pq = (ks * 4 + lq) ^ ((r >> 1) & 7);
                    a[ks][mt] = *(const half8*)&As[cb + r * 64 + pq * 8];
                }
                #pragma unroll
                for (int nf = 0; nf < 2; ++nf) {
                    const int r  = wn + 2 * lm + nf;
                    const int pq = (ks * 4 + lq) ^ ((r >> 1) & 7);
                    b[ks][nf] = *(const half8*)&Bs[cb + r * 64 + pq * 8];
                }
            }
            #pragma unroll
            for (int ks = 0; ks < 2; ++ks)
                #pragma unroll
                for (int mt = 0; mt < 4; ++mt)
                    #pragma unroll
                    for (int nf = 0; nf < 2; ++nf)
                        acc[mt][nf] = __builtin_amdgcn_mfma_f32_16x16x32_f16(
                            a[ks][mt], b[ks][nf], acc[mt][nf], 0, 0, 0);
        }
    }

    #pragma unroll
    for (int mt = 0; mt < 4; ++mt)
        #pragma unroll
        for (int rr = 0; rr < 4; ++rr) {
            const int gr = m0 + wm + mt * 16 + lq * 4 + rr;
            if (gr >= ng) continue;
            const float x0 = fmaxf(acc[mt][0][rr] + bv0, 0.f);
            const float x1 = fmaxf(acc[mt][1][rr] + bv1, 0.f);
            union { uint u; f16 h[2]; } o;
            o.h[0] = (f16)x0; o.h[1] = (f16)x1;
            *(uint*)&Ch[(size_t)(s0 + gr) * NOUT + c] = o.u;
        }
}

// ---------------- fused launches: GEMM tiles first, next layer's transpose after --
__global__ __launch_bounds__(512)
void l1f(const float* __restrict__ z, const f16* __restrict__ W1t,
         const float* __restrict__ b1, f16* __restrict__ h1p,
         const float* __restrict__ W2, f16* __restrict__ W2t,
         const int* __restrict__ seg, const int* __restrict__ perm) {
    __shared__ __align__(16) char sm[65536];
    const int bid = blockIdx.x;
    if (bid < NWG1) {
        const int Lw = (bid & 7) * (NWG1 / 8) + (bid >> 3);   // XCD chunking
        l1_item(Lw, z, W1t, b1, h1p, seg, perm, sm);
    } else {
        t_tile512<H1, H2, H2>(bid - NWG1, W2, W2t, sm);
    }
}

__global__ __launch_bounds__(512)
void g2f(const f16* __restrict__ h1p, const f16* __restrict__ W2t,
         const float* __restrict__ b2, f16* __restrict__ h2p,
         const float* __restrict__ W3, f16* __restrict__ W3t,
         const int* __restrict__ seg, const int* __restrict__ perm) {
    __shared__ __align__(16) char sm[65536];
    const int bid = blockIdx.x;
    if (bid < NWG2) {
        const int Lw = (bid & 7) * (NWG2 / 8) + (bid >> 3);
        gemm8<H1, H2, H2, 8, 8, 0, 0>(Lw, h1p, W2t, b2, h2p, nullptr,
                                      seg, perm, sm);
    } else {
        t_tile512<H2, IMG, IMGP>(bid - NWG2, W3, W3t, sm);
    }
}

__global__ __launch_bounds__(512)
void g3k(const f16* __restrict__ h2p, const f16* __restrict__ W3t,
         const float* __restrict__ b3, float* __restrict__ out,
         const int* __restrict__ seg, const int* __restrict__ perm) {
    __shared__ __align__(16) char sm[65536];
    const int bid = blockIdx.x;
    const int Lw = (bid & 7) * (NWG3 / 8) + (bid >> 3);
    gemm8<H2, IMG, IMGP, 8, 7, 1, 1>(Lw, h2p, W3t, b3, nullptr, out,
                                     seg, perm, sm);
}

extern "C" void kernel_launch(void* const* d_in, const int* in_sizes, int n_in,
                              void* d_out, int out_size, void* d_ws, size_t ws_size,
                              hipStream_t stream) {
    const float* z    = (const float*)d_in[0];
    const int*   gidx = (const int*)  d_in[1];
    const float* W1   = (const float*)d_in[2];
    const float* b1   = (const float*)d_in[3];
    const float* W2   = (const float*)d_in[4];
    const float* b2   = (const float*)d_in[5];
    const float* W3   = (const float*)d_in[6];
    const float* b3   = (const float*)d_in[7];
    float* out = (float*)d_out;

    char* ws = (char*)d_ws;
    size_t off = 0;
    auto alloc = [&](size_t bytes) { size_t o = off; off = (off + bytes + 255) & ~255ULL; return o; };
    int* seg  = (int*)(ws + alloc((size_t)(NGEN + 1) * 4));
    int* perm = (int*)(ws + alloc((size_t)(BATCH + MPAD) * 4));
    f16* h1p = (f16*)(ws + alloc((size_t)(BATCH + MPAD) * H1 * 2));
    f16* h2p = (f16*)(ws + alloc((size_t)(BATCH + MPAD) * H2 * 2));
    f16* W1t = (f16*)(ws + alloc((size_t)NGEN * H1 * NZ * 2));
    f16* W2t = (f16*)(ws + alloc((size_t)NGEN * H2 * H1 * 2));
    f16* W3t = (f16*)(ws + alloc((size_t)NGEN * IMGP * H2 * 2));

    // K1: hist + W1 transpose
    prep1<<<dim3(1 + TB1), dim3(256), 0, stream>>>(W1, W1t, gidx, seg, perm);
    // K2: layer-1 GEMM + W2 transpose backfill
    l1f<<<dim3(NWG1 + TB2), dim3(512), 0, stream>>>(z, W1t, b1, h1p, W2, W2t,
                                                    seg, perm);
    // K3: layer-2 GEMM + W3 transpose backfill
    g2f<<<dim3(NWG2 + TB3), dim3(512), 0, stream>>>(h1p, W2t, b2, h2p, W3, W3t,
                                                    seg, perm);
    // K4: layer-3 GEMM (tanh + scatter)
    g3k<<<dim3(NWG3), dim3(512), 0, stream>>>(h2p, W3t, b3, out, seg, perm);
}

// Round 10
// 160.717 us; speedup vs baseline: 2.4125x; 2.4125x over previous
//
#include <hip/hip_runtime.h>
#include <math.h>

#define NZ    128
#define H1    512
#define H2    1024
#define IMG   784
#define IMGP  896     // layer-3 N padded to 7*128
#define BATCH 4096
#define NGEN  10
#define MPAD  128     // packed-row slack so tail tiles can stage past ng

typedef _Float16 f16;
typedef __attribute__((ext_vector_type(8))) _Float16 half8;
typedef __attribute__((ext_vector_type(4))) float floatx4;

// transpose tile counts (64x64 tiles)
#define TB1 ((NZ / 64) * (H1 / 64) * NGEN)    // 160
#define TB2 ((H1 / 64) * (H2 / 64) * NGEN)    // 1280
#define TB3 ((H2 / 64) * (IMGP / 64) * NGEN)  // 2240

// GEMM logical grids (NM=8 m-tiles covers any bucket <= 1024 rows)
#define NWG1 (8 * 4 * NGEN)                   // 320
#define NWG2 (8 * 8 * NGEN)                   // 640
#define NWG3 (8 * 7 * NGEN)                   // 560

__device__ __forceinline__ void cp16(void* l, const void* g) {
    __builtin_amdgcn_global_load_lds((const __attribute__((address_space(1))) void*)g,
                                     (__attribute__((address_space(3))) void*)l, 16, 0, 0);
}

// ---------------- 256-thread transpose tile (prep1 only) ----------------
template<int K, int N, int NPAD>
__device__ void t_tile256(int idx, const float* __restrict__ W,
                          f16* __restrict__ Wt, f16 (*L)[72]) {
    constexpr int KT = K / 64, NTt = NPAD / 64;
    const int g  = idx / (KT * NTt);
    const int r2 = idx % (KT * NTt);
    const int k0 = (r2 % KT) * 64;
    const int n0 = (r2 / KT) * 64;
    const int t = threadIdx.x;
    {
        const int kk0 = t >> 4, nq = (t & 15) * 4;
        #pragma unroll
        for (int it = 0; it < 4; ++it) {
            const int kk = kk0 + it * 16;
            float4 v = make_float4(0.f, 0.f, 0.f, 0.f);
            if (n0 + nq < N)               // N % 4 == 0: quads never straddle
                v = *(const float4*)(W + ((size_t)g * K + (k0 + kk)) * N + n0 + nq);
            L[nq + 0][kk] = (f16)v.x;
            L[nq + 1][kk] = (f16)v.y;
            L[nq + 2][kk] = (f16)v.z;
            L[nq + 3][kk] = (f16)v.w;
        }
    }
    __syncthreads();
    {
        const int nn0 = t >> 3, kq = (t & 7) * 8;
        #pragma unroll
        for (int it = 0; it < 2; ++it) {
            const int nn = nn0 + it * 32;
            *(half8*)(Wt + ((size_t)g * NPAD + (n0 + nn)) * K + k0 + kq) =
                *(const half8*)&L[nn][kq];
        }
    }
}

// ---------------- 512-thread transpose tile (fused into GEMM launches) ----------
template<int K, int N, int NPAD>
__device__ void t_tile512(int idx, const float* __restrict__ W,
                          f16* __restrict__ Wt, char* smraw) {
    f16 (*L)[72] = (f16(*)[72])smraw;      // 9 KB of the LDS union
    constexpr int KT = K / 64, NTt = NPAD / 64;
    const int g  = idx / (KT * NTt);
    const int r2 = idx % (KT * NTt);
    const int k0 = (r2 % KT) * 64;
    const int n0 = (r2 / KT) * 64;
    const int t = threadIdx.x;
    {
        const int kk0 = t >> 4;            // 0..31
        const int nq  = (t & 15) * 4;
        #pragma unroll
        for (int it = 0; it < 2; ++it) {
            const int kk = kk0 + it * 32;
            float4 v = make_float4(0.f, 0.f, 0.f, 0.f);
            if (n0 + nq < N)
                v = *(const float4*)(W + ((size_t)g * K + (k0 + kk)) * N + n0 + nq);
            L[nq + 0][kk] = (f16)v.x;
            L[nq + 1][kk] = (f16)v.y;
            L[nq + 2][kk] = (f16)v.z;
            L[nq + 3][kk] = (f16)v.w;
        }
    }
    __syncthreads();
    {
        const int nn = t >> 3, kq = (t & 7) * 8;   // 64 rows x 8 quads = 512
        *(half8*)(Wt + ((size_t)g * NPAD + (n0 + nn)) * K + k0 + kq) =
            *(const half8*)&L[nn][kq];
    }
}

// ---------------- prep1: block 0 = hist+perm, blocks 1.. = W1 transpose ----------
__global__ __launch_bounds__(256)
void prep1(const float* __restrict__ W1, f16* __restrict__ W1t,
           const int* __restrict__ g_idx, int* __restrict__ seg,
           int* __restrict__ perm) {
    __shared__ f16 L[64][72];
    __shared__ int lc[NGEN];
    __shared__ int lb[NGEN + 1];
    const int bid = blockIdx.x;
    if (bid == 0) {
        const int t = threadIdx.x;
        if (t < NGEN) lc[t] = 0;
        __syncthreads();
        int gv[BATCH / 256];
        #pragma unroll
        for (int i = 0; i < BATCH / 256; ++i) {
            gv[i] = g_idx[t + i * 256];
            atomicAdd(&lc[gv[i]], 1);
        }
        __syncthreads();
        if (t == 0) {
            int s = 0;
            for (int g = 0; g < NGEN; ++g) { lb[g] = s; s += lc[g]; }
            lb[NGEN] = s;
        }
        __syncthreads();
        if (t <= NGEN) seg[t] = lb[t];
        if (t < NGEN) lc[t] = lb[t];      // reuse as cursors
        __syncthreads();
        #pragma unroll
        for (int i = 0; i < BATCH / 256; ++i) {
            int p = atomicAdd(&lc[gv[i]], 1);
            perm[p] = t + i * 256;
        }
        return;
    }
    t_tile256<NZ, H1, H1>(bid - 1, W1, W1t, L);
}

// ---------------- 8-wave 128x128 GEMM, 3-buffer ring + cross-step frag pipeline --
// r9 measurement: g3k 21.7 µs real at MfmaUtil 16%, ~2900 cyc/K-step vs a
// 768-cyc LDS-port floor -- the r8 schedule serialized reads -> bar ->
// stage -> MFMA. This version overlaps them:
//   step kc: [frags kc already in regs; tile kc+1 landed; tile kc+2 in
//   flight; buf[kc%3] confirmed-read by all waves (last barrier)]
//     stage(kc+3) -> buf[kc%3]          (DMA fills the freed buffer)
//     ds_read frags kc+1 -> other reg set (12 x b128, from buf[(kc+1)%3])
//     16 x MFMA on frags kc  (setprio(1), runs while LDS serves the reads)
//     lgkmcnt(0)  -> frag regs ready     (per-wave)
//     vmcnt(4)    -> tile kc+2 landed; tile kc+3 stays IN FLIGHT across bar
//     s_barrier   -> one barrier/step
// Never vmcnt(0) in the main loop (T4). LDS = 3 x (16K A + 16K B) = 96 KB
// (1 block/CU; the in-block pipeline replaces cross-block TLP).
// LDS XOR-swizzle: phys k-quad = logical ^ ((row>>1)&7). Epilogue/B-col map
// identical to r8 -> bit-identical results.
template<int K, int NOUT, int NPADB, int NM, int NN, int ACT, int SCATTER>
__device__ void gemm8(int Lw, const f16* __restrict__ Ap,
                      const f16* __restrict__ Wt, const float* __restrict__ bias,
                      f16* __restrict__ Ch, float* __restrict__ Cout,
                      const int* __restrict__ seg, const int* __restrict__ perm,
                      char* smraw) {
    constexpr int NT = K / 64;
    static_assert(NT >= 4 && (NT & 1) == 0, "pipeline assumes even NT >= 4");
    const int g   = Lw / (NM * NN);
    const int rem = Lw - g * (NM * NN);
    const int nt  = rem / NM;
    const int mt0 = rem - nt * NM;
    const int s0 = seg[g];
    const int ng = seg[g + 1] - s0;
    const int m0 = mt0 * 128;
    if (m0 >= ng) return;                 // block-uniform early exit
    const int n0 = nt * 128;

    f16* As = (f16*)smraw;                // [3][8192] f16 (48 KB)
    f16* Bs = (f16*)(smraw + 49152);      // [3][8192] f16 (48 KB)
    const int tid = threadIdx.x, lane = tid & 63, w = tid >> 6;

    const f16* ga[2]; const f16* gb[2]; int lo[2];
    #pragma unroll
    for (int j = 0; j < 2; ++j) {
        const int r   = w * 16 + j * 8 + (lane >> 3);
        const int swz = ((lane & 7) ^ ((r >> 1) & 7)) * 8;
        ga[j] = Ap + (size_t)(s0 + m0 + r) * K + swz;
        gb[j] = Wt + ((size_t)g * NPADB + n0 + r) * K + swz;
        lo[j] = (w * 16 + j * 8) * 64;
    }

    const int wm = (w & 1) * 64, wn = (w >> 1) * 32;
    const int lm = lane & 15, lq = lane >> 4;

    // bias preload (oldest VMEM -> drained by the first counted vmcnt)
    const int c = n0 + wn + 2 * lm;
    const bool in0 = (!SCATTER) || (c < NOUT);
    const float* bg = bias + (size_t)g * NOUT;
    const float bv0 = in0 ? bg[c]     : 0.f;
    const float bv1 = in0 ? bg[c + 1] : 0.f;

    floatx4 acc[4][2] = {};
    half8 uA[2][4], uB[2][2], vA[2][4], vB[2][2];   // two frag sets, static-indexed

    auto stage = [&](int t, int b) {
        #pragma unroll
        for (int j = 0; j < 2; ++j) cp16(&As[b * 8192 + lo[j]], ga[j] + (size_t)t * 64);
        #pragma unroll
        for (int j = 0; j < 2; ++j) cp16(&Bs[b * 8192 + lo[j]], gb[j] + (size_t)t * 64);
    };
    auto ldf = [&](int b3, half8 (&fa)[2][4], half8 (&fb)[2][2]) {
        #pragma unroll
        for (int ks = 0; ks < 2; ++ks) {
            #pragma unroll
            for (int mt = 0; mt < 4; ++mt) {
                const int r  = wm + mt * 16 + lm;
                const int pq = (ks * 4 + lq) ^ ((r >> 1) & 7);
                fa[ks][mt] = *(const half8*)&As[b3 * 8192 + r * 64 + pq * 8];
            }
            #pragma unroll
            for (int nf = 0; nf < 2; ++nf) {
                const int r  = wn + 2 * lm + nf;
                const int pq = (ks * 4 + lq) ^ ((r >> 1) & 7);
                fb[ks][nf] = *(const half8*)&Bs[b3 * 8192 + r * 64 + pq * 8];
            }
        }
    };
    auto domf = [&](half8 (&fa)[2][4], half8 (&fb)[2][2]) {
        __builtin_amdgcn_s_setprio(1);
        #pragma unroll
        for (int ks = 0; ks < 2; ++ks)
            #pragma unroll
            for (int mt = 0; mt < 4; ++mt)
                #pragma unroll
                for (int nf = 0; nf < 2; ++nf)
                    acc[mt][nf] = __builtin_amdgcn_mfma_f32_16x16x32_f16(
                        fa[ks][mt], fb[ks][nf], acc[mt][nf], 0, 0, 0);
        __builtin_amdgcn_s_setprio(0);
    };
    auto stepk = [&](int kc, int cur, int nxt,
                     half8 (&ua)[2][4], half8 (&ub)[2][2],
                     half8 (&la)[2][4], half8 (&lb)[2][2]) {
        if (kc + 3 < NT) stage(kc + 3, cur);         // buf[kc%3] freed last barrier
        if (kc + 1 < NT) ldf(nxt, la, lb);           // tile kc+1: landed + visible
        __builtin_amdgcn_sched_barrier(0);
        domf(ua, ub);                                // MFMA overlaps the ds_reads
        asm volatile("s_waitcnt lgkmcnt(0)" ::: "memory");
        __builtin_amdgcn_sched_barrier(0);
        if (kc + 2 < NT) {
            if (kc + 3 < NT) asm volatile("s_waitcnt vmcnt(4)" ::: "memory");
            else             asm volatile("s_waitcnt vmcnt(0)" ::: "memory");
            __builtin_amdgcn_sched_barrier(0);
        }
        if (kc + 1 < NT) {
            __builtin_amdgcn_s_barrier();            // ONE barrier per step
            __builtin_amdgcn_sched_barrier(0);
        }
    };

    // prologue: fill the 3-buffer ring; confirm tiles 0,1; frags0 -> regs
    stage(0, 0);
    __builtin_amdgcn_sched_barrier(0);
    stage(1, 1);
    __builtin_amdgcn_sched_barrier(0);
    stage(2, 2);
    asm volatile("s_waitcnt vmcnt(4)" ::: "memory"); // bias+t0+t1 drained; t2 in flight
    __builtin_amdgcn_sched_barrier(0);
    __builtin_amdgcn_s_barrier();                    // t0,t1 visible to all waves
    __builtin_amdgcn_sched_barrier(0);
    ldf(0, uA, uB);
    asm volatile("s_waitcnt lgkmcnt(0)" ::: "memory");
    __builtin_amdgcn_sched_barrier(0);
    __builtin_amdgcn_s_barrier();                    // frags0 read by ALL -> b0 free
    __builtin_amdgcn_sched_barrier(0);

    int cur = 0;
    for (int kc = 0; kc < NT; kc += 2) {
        const int n1 = (cur >= 2) ? cur - 2 : cur + 1;   // (cur+1)%3
        stepk(kc,     cur, n1, uA, uB, vA, vB);
        const int n2 = (n1 >= 2) ? n1 - 2 : n1 + 1;
        stepk(kc + 1, n1,  n2, vA, vB, uA, uB);
        cur = n2;
    }

    // epilogue: C/D row = (lane>>4)*4 + reg; cols c, c+1.
    #pragma unroll
    for (int mt = 0; mt < 4; ++mt)
        #pragma unroll
        for (int rr = 0; rr < 4; ++rr) {
            const int gr = m0 + wm + mt * 16 + lq * 4 + rr;
            if (gr >= ng) continue;
            float x0 = acc[mt][0][rr] + bv0;
            float x1 = acc[mt][1][rr] + bv1;
            if (ACT == 0) {
                x0 = fmaxf(x0, 0.f); x1 = fmaxf(x1, 0.f);
            } else {                      // tanh, inf-safe
                const float e0 = __expf(2.f * x0);
                const float e1 = __expf(2.f * x1);
                x0 = 1.f - 2.f / (e0 + 1.f);
                x1 = 1.f - 2.f / (e1 + 1.f);
            }
            if (SCATTER) {
                if (in0) {
                    const size_t orow = (size_t)perm[s0 + gr];
                    *(float2*)&Cout[orow * NOUT + c] = make_float2(x0, x1);
                }
            } else {
                union { uint u; f16 h[2]; } o;
                o.h[0] = (f16)x0; o.h[1] = (f16)x1;
                *(uint*)&Ch[(size_t)(s0 + gr) * NOUT + c] = o.u;
            }
        }
}

// ---------------- layer-1 item (512 threads): K=128, both tiles up-front --------
__device__ void l1_item(int Lw, const float* __restrict__ Az,
                        const f16* __restrict__ Wt, const float* __restrict__ bias,
                        f16* __restrict__ Ch, const int* __restrict__ seg,
                        const int* __restrict__ perm, char* smraw) {
    constexpr int K = NZ, NOUT = H1, NPADB = H1, NM = 8, NN = 4;
    const int g   = Lw / (NM * NN);
    const int rem = Lw - g * (NM * NN);
    const int nt  = rem / NM;
    const int mt0 = rem - nt * NM;
    const int s0 = seg[g];
    const int ng = seg[g + 1] - s0;
    const int m0 = mt0 * 128;
    if (m0 >= ng) return;
    const int n0 = nt * 128;

    f16* As = (f16*)smraw;
    f16* Bs = (f16*)(smraw + 32768);
    const int tid = threadIdx.x, lane = tid & 63, w = tid >> 6;

    // B: both K-tiles via cp16; wave w stages rows [w*16, w*16+16)
    #pragma unroll
    for (int j = 0; j < 2; ++j) {
        const int r   = w * 16 + j * 8 + (lane >> 3);
        const int swz = ((lane & 7) ^ ((r >> 1) & 7)) * 8;
        const f16* gbj = Wt + ((size_t)g * NPADB + n0 + r) * K + swz;
        const int  loj = (w * 16 + j * 8) * 64;
        cp16(&Bs[loj],        gbj);
        cp16(&Bs[8192 + loj], gbj + 64);
    }
    // A: gather z rows via perm, convert f32->f16, swizzled ds_write.
    const int arow = tid >> 3, aq = tid & 7;
    #pragma unroll
    for (int p = 0; p < 2; ++p) {
        const int r   = arow + p * 64;
        const int prw = perm[min(s0 + m0 + r, BATCH - 1)];  // clamp off slack
        #pragma unroll
        for (int t = 0; t < 2; ++t) {
            const float* src = Az + (size_t)prw * K + t * 64 + aq * 8;
            const float4 v0 = *(const float4*)src;
            const float4 v1 = *(const float4*)(src + 4);
            half8 h;
            h[0] = (f16)v0.x; h[1] = (f16)v0.y; h[2] = (f16)v0.z; h[3] = (f16)v0.w;
            h[4] = (f16)v1.x; h[5] = (f16)v1.y; h[6] = (f16)v1.z; h[7] = (f16)v1.w;
            const int pq = aq ^ ((r >> 1) & 7);
            *(half8*)&As[t * 8192 + r * 64 + pq * 8] = h;
        }
    }

    const int wm = (w & 1) * 64, wn = (w >> 1) * 32;
    const int lm = lane & 15, lq = lane >> 4;
    const int c = n0 + wn + 2 * lm;
    const float* bg = bias + (size_t)g * NOUT;
    const float bv0 = bg[c], bv1 = bg[c + 1];

    __syncthreads();                      // drains cp16 + ds_write

    floatx4 acc[4][2] = {};
    #pragma unroll
    for (int kc = 0; kc < 2; ++kc) {
        const int cb = kc * 8192;
        half8 a[2][4], b[2][2];
        #pragma unroll
        for (int ks = 0; ks < 2; ++ks) {
            #pragma unroll
            for (int mt = 0; mt < 4; ++mt) {
                const int r  = wm + mt * 16 + lm;
                const int pq = (ks * 4 + lq) ^ ((r >> 1) & 7);
                a[ks][mt] = *(const half8*)&As[cb + r * 64 + pq * 8];
            }
            #pragma unroll
            for (int nf = 0; nf < 2; ++nf) {
                const int r  = wn + 2 * lm + nf;
                const int pq = (ks * 4 + lq) ^ ((r >> 1) & 7);
                b[ks][nf] = *(const half8*)&Bs[cb + r * 64 + pq * 8];
            }
        }
        #pragma unroll
        for (int ks = 0; ks < 2; ++ks)
            #pragma unroll
            for (int mt = 0; mt < 4; ++mt)
                #pragma unroll
                for (int nf = 0; nf < 2; ++nf)
                    acc[mt][nf] = __builtin_amdgcn_mfma_f32_16x16x32_f16(
                        a[ks][mt], b[ks][nf], acc[mt][nf], 0, 0, 0);
    }

    #pragma unroll
    for (int mt = 0; mt < 4; ++mt)
        #pragma unroll
        for (int rr = 0; rr < 4; ++rr) {
            const int gr = m0 + wm + mt * 16 + lq * 4 + rr;
            if (gr >= ng) continue;
            const float x0 = fmaxf(acc[mt][0][rr] + bv0, 0.f);
            const float x1 = fmaxf(acc[mt][1][rr] + bv1, 0.f);
            union { uint u; f16 h[2]; } o;
            o.h[0] = (f16)x0; o.h[1] = (f16)x1;
            *(uint*)&Ch[(size_t)(s0 + gr) * NOUT + c] = o.u;
        }
}

// ---------------- fused launches: GEMM tiles first, next layer's transpose after --
__global__ __launch_bounds__(512)
void l1f(const float* __restrict__ z, const f16* __restrict__ W1t,
         const float* __restrict__ b1, f16* __restrict__ h1p,
         const float* __restrict__ W2, f16* __restrict__ W2t,
         const int* __restrict__ seg, const int* __restrict__ perm) {
    __shared__ __align__(16) char sm[65536];
    const int bid = blockIdx.x;
    if (bid < NWG1) {
        const int Lw = (bid & 7) * (NWG1 / 8) + (bid >> 3);   // XCD chunking
        l1_item(Lw, z, W1t, b1, h1p, seg, perm, sm);
    } else {
        t_tile512<H1, H2, H2>(bid - NWG1, W2, W2t, sm);
    }
}

__global__ __launch_bounds__(512)
void g2f(const f16* __restrict__ h1p, const f16* __restrict__ W2t,
         const float* __restrict__ b2, f16* __restrict__ h2p,
         const float* __restrict__ W3, f16* __restrict__ W3t,
         const int* __restrict__ seg, const int* __restrict__ perm) {
    __shared__ __align__(16) char sm[98304];   // 96 KB: 3-buffer ring
    const int bid = blockIdx.x;
    if (bid < NWG2) {
        const int Lw = (bid & 7) * (NWG2 / 8) + (bid >> 3);
        gemm8<H1, H2, H2, 8, 8, 0, 0>(Lw, h1p, W2t, b2, h2p, nullptr,
                                      seg, perm, sm);
    } else {
        t_tile512<H2, IMG, IMGP>(bid - NWG2, W3, W3t, sm);
    }
}

__global__ __launch_bounds__(512)
void g3k(const f16* __restrict__ h2p, const f16* __restrict__ W3t,
         const float* __restrict__ b3, float* __restrict__ out,
         const int* __restrict__ seg, const int* __restrict__ perm) {
    __shared__ __align__(16) char sm[98304];   // 96 KB: 3-buffer ring
    const int bid = blockIdx.x;
    const int Lw = (bid & 7) * (NWG3 / 8) + (bid >> 3);
    gemm8<H2, IMG, IMGP, 8, 7, 1, 1>(Lw, h2p, W3t, b3, nullptr, out,
                                     seg, perm, sm);
}

extern "C" void kernel_launch(void* const* d_in, const int* in_sizes, int n_in,
                              void* d_out, int out_size, void* d_ws, size_t ws_size,
                              hipStream_t stream) {
    const float* z    = (const float*)d_in[0];
    const int*   gidx = (const int*)  d_in[1];
    const float* W1   = (const float*)d_in[2];
    const float* b1   = (const float*)d_in[3];
    const float* W2   = (const float*)d_in[4];
    const float* b2   = (const float*)d_in[5];
    const float* W3   = (const float*)d_in[6];
    const float* b3   = (const float*)d_in[7];
    float* out = (float*)d_out;

    char* ws = (char*)d_ws;
    size_t off = 0;
    auto alloc = [&](size_t bytes) { size_t o = off; off = (off + bytes + 255) & ~255ULL; return o; };
    int* seg  = (int*)(ws + alloc((size_t)(NGEN + 1) * 4));
    int* perm = (int*)(ws + alloc((size_t)(BATCH + MPAD) * 4));
    f16* h1p = (f16*)(ws + alloc((size_t)(BATCH + MPAD) * H1 * 2));
    f16* h2p = (f16*)(ws + alloc((size_t)(BATCH + MPAD) * H2 * 2));
    f16* W1t = (f16*)(ws + alloc((size_t)NGEN * H1 * NZ * 2));
    f16* W2t = (f16*)(ws + alloc((size_t)NGEN * H2 * H1 * 2));
    f16* W3t = (f16*)(ws + alloc((size_t)NGEN * IMGP * H2 * 2));

    // K1: hist + W1 transpose
    prep1<<<dim3(1 + TB1), dim3(256), 0, stream>>>(W1, W1t, gidx, seg, perm);
    // K2: layer-1 GEMM + W2 transpose backfill
    l1f<<<dim3(NWG1 + TB2), dim3(512), 0, stream>>>(z, W1t, b1, h1p, W2, W2t,
                                                    seg, perm);
    // K3: layer-2 GEMM + W3 transpose backfill
    g2f<<<dim3(NWG2 + TB3), dim3(512), 0, stream>>>(h1p, W2t, b2, h2p, W3, W3t,
                                                    seg, perm);
    // K4: layer-3 GEMM (tanh + scatter)
    g3k<<<dim3(NWG3), dim3(512), 0, stream>>>(h2p, W3t, b3, out, seg, perm);
}

// Round 11
// 156.690 us; speedup vs baseline: 2.4745x; 1.0257x over previous
//
#include <hip/hip_runtime.h>
#include <math.h>

#define NZ    128
#define H1    512
#define H2    1024
#define IMG   784
#define IMGP  896     // layer-3 N padded to 7*128
#define BATCH 4096
#define NGEN  10
#define MPAD  128     // packed-row slack so tail tiles can stage past ng

typedef _Float16 f16;
typedef __attribute__((ext_vector_type(8))) _Float16 half8;
typedef __attribute__((ext_vector_type(4))) float floatx4;

// transpose tile counts (64x64 tiles)
#define TB1 ((NZ / 64) * (H1 / 64) * NGEN)    // 160
#define TB2 ((H1 / 64) * (H2 / 64) * NGEN)    // 1280
#define TB3 ((H2 / 64) * (IMGP / 64) * NGEN)  // 2240

// GEMM logical grids: l1f 128-row m-tiles (NM=8); g2f/g3k 64-row m-tiles (NM=16)
#define NWG1 (8 * 4 * NGEN)                   // 320
#define NWG2 (16 * 8 * NGEN)                  // 1280
#define NWG3 (16 * 7 * NGEN)                  // 1120

__device__ __forceinline__ void cp16(void* l, const void* g) {
    __builtin_amdgcn_global_load_lds((const __attribute__((address_space(1))) void*)g,
                                     (__attribute__((address_space(3))) void*)l, 16, 0, 0);
}

// ---------------- 256-thread transpose tile ----------------
template<int K, int N, int NPAD>
__device__ void t_tile256(int idx, const float* __restrict__ W,
                          f16* __restrict__ Wt, f16 (*L)[72]) {
    constexpr int KT = K / 64, NTt = NPAD / 64;
    const int g  = idx / (KT * NTt);
    const int r2 = idx % (KT * NTt);
    const int k0 = (r2 % KT) * 64;
    const int n0 = (r2 / KT) * 64;
    const int t = threadIdx.x;
    {
        const int kk0 = t >> 4, nq = (t & 15) * 4;
        #pragma unroll
        for (int it = 0; it < 4; ++it) {
            const int kk = kk0 + it * 16;
            float4 v = make_float4(0.f, 0.f, 0.f, 0.f);
            if (n0 + nq < N)               // N % 4 == 0: quads never straddle
                v = *(const float4*)(W + ((size_t)g * K + (k0 + kk)) * N + n0 + nq);
            L[nq + 0][kk] = (f16)v.x;
            L[nq + 1][kk] = (f16)v.y;
            L[nq + 2][kk] = (f16)v.z;
            L[nq + 3][kk] = (f16)v.w;
        }
    }
    __syncthreads();
    {
        const int nn0 = t >> 3, kq = (t & 7) * 8;
        #pragma unroll
        for (int it = 0; it < 2; ++it) {
            const int nn = nn0 + it * 32;
            *(half8*)(Wt + ((size_t)g * NPAD + (n0 + nn)) * K + k0 + kq) =
                *(const half8*)&L[nn][kq];
        }
    }
}

// ---------------- 512-thread transpose tile (l1f backfill) ----------
template<int K, int N, int NPAD>
__device__ void t_tile512(int idx, const float* __restrict__ W,
                          f16* __restrict__ Wt, char* smraw) {
    f16 (*L)[72] = (f16(*)[72])smraw;      // 9 KB of the LDS union
    constexpr int KT = K / 64, NTt = NPAD / 64;
    const int g  = idx / (KT * NTt);
    const int r2 = idx % (KT * NTt);
    const int k0 = (r2 % KT) * 64;
    const int n0 = (r2 / KT) * 64;
    const int t = threadIdx.x;
    {
        const int kk0 = t >> 4;            // 0..31
        const int nq  = (t & 15) * 4;
        #pragma unroll
        for (int it = 0; it < 2; ++it) {
            const int kk = kk0 + it * 32;
            float4 v = make_float4(0.f, 0.f, 0.f, 0.f);
            if (n0 + nq < N)
                v = *(const float4*)(W + ((size_t)g * K + (k0 + kk)) * N + n0 + nq);
            L[nq + 0][kk] = (f16)v.x;
            L[nq + 1][kk] = (f16)v.y;
            L[nq + 2][kk] = (f16)v.z;
            L[nq + 3][kk] = (f16)v.w;
        }
    }
    __syncthreads();
    {
        const int nn = t >> 3, kq = (t & 7) * 8;   // 64 rows x 8 quads = 512
        *(half8*)(Wt + ((size_t)g * NPAD + (n0 + nn)) * K + k0 + kq) =
            *(const half8*)&L[nn][kq];
    }
}

// ---------------- prep1: block 0 = hist+perm, blocks 1.. = W1 transpose ----------
__global__ __launch_bounds__(256)
void prep1(const float* __restrict__ W1, f16* __restrict__ W1t,
           const int* __restrict__ g_idx, int* __restrict__ seg,
           int* __restrict__ perm) {
    __shared__ f16 L[64][72];
    __shared__ int lc[NGEN];
    __shared__ int lb[NGEN + 1];
    const int bid = blockIdx.x;
    if (bid == 0) {
        const int t = threadIdx.x;
        if (t < NGEN) lc[t] = 0;
        __syncthreads();
        int gv[BATCH / 256];
        #pragma unroll
        for (int i = 0; i < BATCH / 256; ++i) {
            gv[i] = g_idx[t + i * 256];
            atomicAdd(&lc[gv[i]], 1);
        }
        __syncthreads();
        if (t == 0) {
            int s = 0;
            for (int g = 0; g < NGEN; ++g) { lb[g] = s; s += lc[g]; }
            lb[NGEN] = s;
        }
        __syncthreads();
        if (t <= NGEN) seg[t] = lb[t];
        if (t < NGEN) lc[t] = lb[t];      // reuse as cursors
        __syncthreads();
        #pragma unroll
        for (int i = 0; i < BATCH / 256; ++i) {
            int p = atomicAdd(&lc[gv[i]], 1);
            perm[p] = t + i * 256;
        }
        return;
    }
    t_tile256<NZ, H1, H1>(bid - 1, W1, W1t, L);
}

// ---------------- 4-wave 64x128 GEMM, counted-vmcnt 2-buffer (r8 schedule) -------
// 256 threads = 4 waves in 1m x 4n; each wave 64x32 output (acc[4][2]) --
// identical per-wave work to the r8 8-wave kernel (12 ds_read_b128 + 16 MFMA
// per step), but the block is HALF the tile: LDS = 2 x (8K A + 16K B) = 48 KB
// -> 3 blocks/CU capacity, 12 waves/CU. r9 measured the r8 g3k at 1.09 live
// blocks/CU with stage/read/MFMA phases serialized (3000 cyc/step vs
// max-component 1400); at ~2 live blocks/CU the phases of independent blocks
// overlap. Staging: A 2 cp16/wave, B 4 cp16/wave -> steady wait vmcnt(6)
// (next tile's 6 loads stay in flight across the barrier; never 0 in-loop).
// LDS XOR-swizzle: phys k-quad = logical ^ ((row>>1)&7) (2-way = free).
// B col map: frag nf -> col wn + 2*lm + nf. Math identical to r8.
template<int K, int NOUT, int NPADB, int NM, int NN, int ACT, int SCATTER>
__device__ void gemm4(int Lw, const f16* __restrict__ Ap,
                      const f16* __restrict__ Wt, const float* __restrict__ bias,
                      f16* __restrict__ Ch, float* __restrict__ Cout,
                      const int* __restrict__ seg, const int* __restrict__ perm,
                      char* smraw) {
    constexpr int NT = K / 64;
    static_assert(NT >= 2, "pipeline assumes K >= 128");
    const int g   = Lw / (NM * NN);
    const int rem = Lw - g * (NM * NN);
    const int nt  = rem / NM;
    const int mt0 = rem - nt * NM;
    const int s0 = seg[g];
    const int ng = seg[g + 1] - s0;
    const int m0 = mt0 * 64;
    if (m0 >= ng) return;                 // block-uniform early exit
    const int n0 = nt * 128;

    f16* As = (f16*)smraw;                // [2][4096] f16 (16 KB)
    f16* Bs = (f16*)(smraw + 16384);      // [2][8192] f16 (32 KB)
    const int tid = threadIdx.x, lane = tid & 63, w = tid >> 6;

    // A staging: wave w stages rows [w*16, w*16+16): 2 cp16
    const f16* ga[2]; int lao[2];
    #pragma unroll
    for (int j = 0; j < 2; ++j) {
        const int r   = w * 16 + j * 8 + (lane >> 3);
        const int swz = ((lane & 7) ^ ((r >> 1) & 7)) * 8;
        ga[j]  = Ap + (size_t)(s0 + m0 + r) * K + swz;
        lao[j] = (w * 16 + j * 8) * 64;
    }
    // B staging: wave w stages rows [w*32, w*32+32): 4 cp16
    const f16* gb[4]; int lbo[4];
    #pragma unroll
    for (int j = 0; j < 4; ++j) {
        const int r   = w * 32 + j * 8 + (lane >> 3);
        const int swz = ((lane & 7) ^ ((r >> 1) & 7)) * 8;
        gb[j]  = Wt + ((size_t)g * NPADB + n0 + r) * K + swz;
        lbo[j] = (w * 32 + j * 8) * 64;
    }

    const int wn = w * 32;
    const int lm = lane & 15, lq = lane >> 4;

    // bias preload (oldest VMEM -> first counted wait drains it with tile 0)
    const int c = n0 + wn + 2 * lm;
    const bool in0 = (!SCATTER) || (c < NOUT);
    const float* bg = bias + (size_t)g * NOUT;
    const float bv0 = in0 ? bg[c]     : 0.f;
    const float bv1 = in0 ? bg[c + 1] : 0.f;

    floatx4 acc[4][2] = {};

    auto stage = [&](int t, int b) {
        #pragma unroll
        for (int j = 0; j < 2; ++j) cp16(&As[b * 4096 + lao[j]], ga[j] + (size_t)t * 64);
        #pragma unroll
        for (int j = 0; j < 4; ++j) cp16(&Bs[b * 8192 + lbo[j]], gb[j] + (size_t)t * 64);
    };
    stage(0, 0);
    __builtin_amdgcn_sched_barrier(0);    // tile0's 6 loads strictly older
    stage(1, 1);

    for (int kc = 0; kc < NT; ++kc) {
        if (kc + 1 < NT) asm volatile("s_waitcnt vmcnt(6)" ::: "memory");
        else             asm volatile("s_waitcnt vmcnt(0)" ::: "memory");
        __builtin_amdgcn_sched_barrier(0);
        __builtin_amdgcn_s_barrier();     // tile kc visible to all waves
        __builtin_amdgcn_sched_barrier(0);

        const int ca = (kc & 1) * 4096, cb = (kc & 1) * 8192;
        half8 a[2][4], b[2][2];
        #pragma unroll
        for (int ks = 0; ks < 2; ++ks) {
            #pragma unroll
            for (int mt = 0; mt < 4; ++mt) {
                const int r  = mt * 16 + lm;
                const int pq = (ks * 4 + lq) ^ ((r >> 1) & 7);
                a[ks][mt] = *(const half8*)&As[ca + r * 64 + pq * 8];
            }
            #pragma unroll
            for (int nf = 0; nf < 2; ++nf) {
                const int r  = wn + 2 * lm + nf;
                const int pq = (ks * 4 + lq) ^ ((r >> 1) & 7);
                b[ks][nf] = *(const half8*)&Bs[cb + r * 64 + pq * 8];
            }
        }
        asm volatile("s_waitcnt lgkmcnt(0)" ::: "memory");
        __builtin_amdgcn_sched_barrier(0);
        if (kc + 2 < NT) {
            __builtin_amdgcn_s_barrier(); // ALL waves' reads done: buffer free
            __builtin_amdgcn_sched_barrier(0);
            stage(kc + 2, kc & 1);
        }
        #pragma unroll
        for (int ks = 0; ks < 2; ++ks)
            #pragma unroll
            for (int mt = 0; mt < 4; ++mt)
                #pragma unroll
                for (int nf = 0; nf < 2; ++nf)
                    acc[mt][nf] = __builtin_amdgcn_mfma_f32_16x16x32_f16(
                        a[ks][mt], b[ks][nf], acc[mt][nf], 0, 0, 0);
    }

    // epilogue: C/D row = (lane>>4)*4 + reg; cols c, c+1.
    #pragma unroll
    for (int mt = 0; mt < 4; ++mt)
        #pragma unroll
        for (int rr = 0; rr < 4; ++rr) {
            const int gr = m0 + mt * 16 + lq * 4 + rr;
            if (gr >= ng) continue;
            float x0 = acc[mt][0][rr] + bv0;
            float x1 = acc[mt][1][rr] + bv1;
            if (ACT == 0) {
                x0 = fmaxf(x0, 0.f); x1 = fmaxf(x1, 0.f);
            } else {                      // tanh, inf-safe
                const float e0 = __expf(2.f * x0);
                const float e1 = __expf(2.f * x1);
                x0 = 1.f - 2.f / (e0 + 1.f);
                x1 = 1.f - 2.f / (e1 + 1.f);
            }
            if (SCATTER) {
                if (in0) {
                    const size_t orow = (size_t)perm[s0 + gr];
                    *(float2*)&Cout[orow * NOUT + c] = make_float2(x0, x1);
                }
            } else {
                union { uint u; f16 h[2]; } o;
                o.h[0] = (f16)x0; o.h[1] = (f16)x1;
                *(uint*)&Ch[(size_t)(s0 + gr) * NOUT + c] = o.u;
            }
        }
}

// ---------------- layer-1 item (512 threads): K=128, both tiles up-front --------
__device__ void l1_item(int Lw, const float* __restrict__ Az,
                        const f16* __restrict__ Wt, const float* __restrict__ bias,
                        f16* __restrict__ Ch, const int* __restrict__ seg,
                        const int* __restrict__ perm, char* smraw) {
    constexpr int K = NZ, NOUT = H1, NPADB = H1, NM = 8, NN = 4;
    const int g   = Lw / (NM * NN);
    const int rem = Lw - g * (NM * NN);
    const int nt  = rem / NM;
    const int mt0 = rem - nt * NM;
    const int s0 = seg[g];
    const int ng = seg[g + 1] - s0;
    const int m0 = mt0 * 128;
    if (m0 >= ng) return;
    const int n0 = nt * 128;

    f16* As = (f16*)smraw;
    f16* Bs = (f16*)(smraw + 32768);
    const int tid = threadIdx.x, lane = tid & 63, w = tid >> 6;

    // B: both K-tiles via cp16; wave w stages rows [w*16, w*16+16)
    #pragma unroll
    for (int j = 0; j < 2; ++j) {
        const int r   = w * 16 + j * 8 + (lane >> 3);
        const int swz = ((lane & 7) ^ ((r >> 1) & 7)) * 8;
        const f16* gbj = Wt + ((size_t)g * NPADB + n0 + r) * K + swz;
        const int  loj = (w * 16 + j * 8) * 64;
        cp16(&Bs[loj],        gbj);
        cp16(&Bs[8192 + loj], gbj + 64);
    }
    // A: gather z rows via perm, convert f32->f16, swizzled ds_write.
    const int arow = tid >> 3, aq = tid & 7;
    #pragma unroll
    for (int p = 0; p < 2; ++p) {
        const int r   = arow + p * 64;
        const int prw = perm[min(s0 + m0 + r, BATCH - 1)];  // clamp off slack
        #pragma unroll
        for (int t = 0; t < 2; ++t) {
            const float* src = Az + (size_t)prw * K + t * 64 + aq * 8;
            const float4 v0 = *(const float4*)src;
            const float4 v1 = *(const float4*)(src + 4);
            half8 h;
            h[0] = (f16)v0.x; h[1] = (f16)v0.y; h[2] = (f16)v0.z; h[3] = (f16)v0.w;
            h[4] = (f16)v1.x; h[5] = (f16)v1.y; h[6] = (f16)v1.z; h[7] = (f16)v1.w;
            const int pq = aq ^ ((r >> 1) & 7);
            *(half8*)&As[t * 8192 + r * 64 + pq * 8] = h;
        }
    }

    const int wm = (w & 1) * 64, wn = (w >> 1) * 32;
    const int lm = lane & 15, lq = lane >> 4;
    const int c = n0 + wn + 2 * lm;
    const float* bg = bias + (size_t)g * NOUT;
    const float bv0 = bg[c], bv1 = bg[c + 1];

    __syncthreads();                      // drains cp16 + ds_write

    floatx4 acc[4][2] = {};
    #pragma unroll
    for (int kc = 0; kc < 2; ++kc) {
        const int cb = kc * 8192;
        half8 a[2][4], b[2][2];
        #pragma unroll
        for (int ks = 0; ks < 2; ++ks) {
            #pragma unroll
            for (int mt = 0; mt < 4; ++mt) {
                const int r  = wm + mt * 16 + lm;
                const int pq = (ks * 4 + lq) ^ ((r >> 1) & 7);
                a[ks][mt] = *(const half8*)&As[cb + r * 64 + pq * 8];
            }
            #pragma unroll
            for (int nf = 0; nf < 2; ++nf) {
                const int r  = wn + 2 * lm + nf;
                const int pq = (ks * 4 + lq) ^ ((r >> 1) & 7);
                b[ks][nf] = *(const half8*)&Bs[cb + r * 64 + pq * 8];
            }
        }
        #pragma unroll
        for (int ks = 0; ks < 2; ++ks)
            #pragma unroll
            for (int mt = 0; mt < 4; ++mt)
                #pragma unroll
                for (int nf = 0; nf < 2; ++nf)
                    acc[mt][nf] = __builtin_amdgcn_mfma_f32_16x16x32_f16(
                        a[ks][mt], b[ks][nf], acc[mt][nf], 0, 0, 0);
    }

    #pragma unroll
    for (int mt = 0; mt < 4; ++mt)
        #pragma unroll
        for (int rr = 0; rr < 4; ++rr) {
            const int gr = m0 + wm + mt * 16 + lq * 4 + rr;
            if (gr >= ng) continue;
            const float x0 = fmaxf(acc[mt][0][rr] + bv0, 0.f);
            const float x1 = fmaxf(acc[mt][1][rr] + bv1, 0.f);
            union { uint u; f16 h[2]; } o;
            o.h[0] = (f16)x0; o.h[1] = (f16)x1;
            *(uint*)&Ch[(size_t)(s0 + gr) * NOUT + c] = o.u;
        }
}

// ---------------- launches ----------------
__global__ __launch_bounds__(512)
void l1f(const float* __restrict__ z, const f16* __restrict__ W1t,
         const float* __restrict__ b1, f16* __restrict__ h1p,
         const float* __restrict__ W2, f16* __restrict__ W2t,
         const int* __restrict__ seg, const int* __restrict__ perm) {
    __shared__ __align__(16) char sm[65536];
    const int bid = blockIdx.x;
    if (bid < NWG1) {
        const int Lw = (bid & 7) * (NWG1 / 8) + (bid >> 3);   // XCD chunking
        l1_item(Lw, z, W1t, b1, h1p, seg, perm, sm);
    } else {
        t_tile512<H1, H2, H2>(bid - NWG1, W2, W2t, sm);
    }
}

__global__ __launch_bounds__(256)
void g2f(const f16* __restrict__ h1p, const f16* __restrict__ W2t,
         const float* __restrict__ b2, f16* __restrict__ h2p,
         const float* __restrict__ W3, f16* __restrict__ W3t,
         const int* __restrict__ seg, const int* __restrict__ perm) {
    __shared__ __align__(16) char sm[49152];   // 48 KB: 3 blocks/CU
    const int bid = blockIdx.x;
    if (bid < NWG2) {
        const int Lw = (bid & 7) * (NWG2 / 8) + (bid >> 3);
        gemm4<H1, H2, H2, 16, 8, 0, 0>(Lw, h1p, W2t, b2, h2p, nullptr,
                                       seg, perm, sm);
    } else {
        t_tile256<H2, IMG, IMGP>(bid - NWG2, W3, W3t, (f16(*)[72])sm);
    }
}

__global__ __launch_bounds__(256)
void g3k(const f16* __restrict__ h2p, const f16* __restrict__ W3t,
         const float* __restrict__ b3, float* __restrict__ out,
         const int* __restrict__ seg, const int* __restrict__ perm) {
    __shared__ __align__(16) char sm[49152];   // 48 KB: 3 blocks/CU
    const int bid = blockIdx.x;
    const int Lw = (bid & 7) * (NWG3 / 8) + (bid >> 3);
    gemm4<H2, IMG, IMGP, 16, 7, 1, 1>(Lw, h2p, W3t, b3, nullptr, out,
                                      seg, perm, sm);
}

extern "C" void kernel_launch(void* const* d_in, const int* in_sizes, int n_in,
                              void* d_out, int out_size, void* d_ws, size_t ws_size,
                              hipStream_t stream) {
    const float* z    = (const float*)d_in[0];
    const int*   gidx = (const int*)  d_in[1];
    const float* W1   = (const float*)d_in[2];
    const float* b1   = (const float*)d_in[3];
    const float* W2   = (const float*)d_in[4];
    const float* b2   = (const float*)d_in[5];
    const float* W3   = (const float*)d_in[6];
    const float* b3   = (const float*)d_in[7];
    float* out = (float*)d_out;

    char* ws = (char*)d_ws;
    size_t off = 0;
    auto alloc = [&](size_t bytes) { size_t o = off; off = (off + bytes + 255) & ~255ULL; return o; };
    int* seg  = (int*)(ws + alloc((size_t)(NGEN + 1) * 4));
    int* perm = (int*)(ws + alloc((size_t)(BATCH + MPAD) * 4));
    f16* h1p = (f16*)(ws + alloc((size_t)(BATCH + MPAD) * H1 * 2));
    f16* h2p = (f16*)(ws + alloc((size_t)(BATCH + MPAD) * H2 * 2));
    f16* W1t = (f16*)(ws + alloc((size_t)NGEN * H1 * NZ * 2));
    f16* W2t = (f16*)(ws + alloc((size_t)NGEN * H2 * H1 * 2));
    f16* W3t = (f16*)(ws + alloc((size_t)NGEN * IMGP * H2 * 2));

    // K1: hist + W1 transpose
    prep1<<<dim3(1 + TB1), dim3(256), 0, stream>>>(W1, W1t, gidx, seg, perm);
    // K2: layer-1 GEMM + W2 transpose backfill (r8-proven form)
    l1f<<<dim3(NWG1 + TB2), dim3(512), 0, stream>>>(z, W1t, b1, h1p, W2, W2t,
                                                    seg, perm);
    // K3: layer-2 GEMM (64x128 tiles, 3 blocks/CU) + W3 transpose backfill
    g2f<<<dim3(NWG2 + TB3), dim3(256), 0, stream>>>(h1p, W2t, b2, h2p, W3, W3t,
                                                    seg, perm);
    // K4: layer-3 GEMM (64x128 tiles, 3 blocks/CU; tanh + scatter)
    g3k<<<dim3(NWG3), dim3(256), 0, stream>>>(h2p, W3t, b3, out, seg, perm);
}